// Round 5
// baseline (318.589 us; speedup 1.0000x reference)
//
#include <hip/hip_runtime.h>
#include <hip/hip_bf16.h>

typedef __bf16 bf16x8 __attribute__((ext_vector_type(8)));
typedef __bf16 bf16x4 __attribute__((ext_vector_type(4)));
typedef float  f32x4  __attribute__((ext_vector_type(4)));

#define MFMA16(a,b,c) __builtin_amdgcn_mfma_f32_16x16x32_bf16((a),(b),(c),0,0,0)

// LDS-only barrier: leaves the global u-prefetch vmcnt outstanding.
__device__ __forceinline__ void barrier_lds() {
  asm volatile("s_waitcnt lgkmcnt(0)\n\ts_barrier" ::: "memory");
}

constexpr int Bb = 2048, Tt = 80, Ee = 100, Uu = 256;
constexpr int BM = 8;          // batch rows per block
constexpr int RNT = 1024;      // 16 waves, 4 waves/SIMD
constexpr int HCH = 256;       // elems per k-chunk (32 k x 8 rows)
constexpr int HB = 8 * HCH;    // one h buffer

template<bool ISBF>
__device__ __forceinline__ float ldf(const void* p, int i) {
  if constexpr (ISBF) return (float)((const __bf16*)p)[i];
  else                return ((const float*)p)[i];
}

__device__ __forceinline__ float fast_tanh(float x) {
  float e = __expf(2.f * x);
  return 1.f - 2.f / (e + 1.f);
}

// In-kernel dtype detect: f32 storage -> low 16-bit halves decode as bf16
// with wild exponents ~84% of the time; genuine bf16 N(0,1/16) never does.
__device__ __forceinline__ bool detect_bf16(const void* wh) {
  const unsigned short* u = (const unsigned short*)wh;
  int c = 0;
  const int lane = threadIdx.x & 63;
  #pragma unroll
  for (int r = 0; r < 4; ++r) {
    unsigned short h = u[2 * (lane + 64 * r)];
    int ex = (h >> 7) & 0xFF;
    if (ex >= 135 || (ex >= 1 && ex <= 95)) c++;
  }
  #pragma unroll
  for (int o = 32; o >= 1; o >>= 1) c += __shfl_down(c, o, 64);
  return __shfl(c, 0, 64) < 64;
}

// ---------------- persistent 2-layer RNN with fused U-production -----------
// R5 = R3 with the weight-fragment pin REMOVED.
// R3 post-mortem: "+v" pin forced 96 weight regs into the 64-entry arch
// budget -> allocator parked them in AGPR and emitted v_accvgpr_read copies
// per MFMA (VALUBusy 43%, MfmaUtil 27.7%). R4's "+a" pin miscompiled.
// MFMA srcB is an AV-class operand (VGPR or AGPR): with NO constraint the
// allocator can place live-through-loop weight frags in AGPR directly, zero
// per-use cost. 96 AGPR weights + ~30 arch VGPR working set fits 128 cap.
template<bool ISBF>
__launch_bounds__(RNT, 4)
__global__ void rnn_kernel(const int* __restrict__ tokens,
                           const void* __restrict__ emb,
                           const void* __restrict__ Wx0,
                           const void* __restrict__ Wx1,
                           const void* __restrict__ Wh,
                           const void* __restrict__ bias,
                           const void* __restrict__ h0g,
                           const void* __restrict__ Wo,
                           const void* __restrict__ bo,
                           __bf16* __restrict__ U,
                           void* __restrict__ out) {
  if (detect_bf16(Wh) != ISBF) return;   // wrong-dtype instantiation exits

  __shared__ __align__(16) __bf16 s_h0[2 * HB];
  __shared__ __align__(16) __bf16 s_h1[2 * HB];
  __shared__ int s_tok[BM * Tt];

  const int tid = threadIdx.x, lane = tid & 63, wv = tid >> 6;  // wv 0..15
  const int m = lane & 15, kc = lane >> 4, hf = lane >> 5;
  const int mh = (m >> 3) & 1;           // packed-A source: 0=h0n, 1=h1
  const int rb = blockIdx.x, b0 = rb * BM;
  const int au2 = (kc * 8 + (m & 7)) * 8;  // A-read offset (row m&7, ksub kc)

  // permlane32_swap operand-semantics probe (wave-uniform, 2 instrs):
  // form A: vdst.upper <-> vsrc.lower ; form B: vdst.lower <-> vsrc.upper.
  int pv = lane, qv = 64 + lane;
  asm volatile("v_permlane32_swap_b32 %0, %1" : "+v"(pv), "+v"(qv));
  const bool forma = (__shfl(pv, 0, 64) == 0);  // lane0 pv unchanged => A

  for (int idx = tid; idx < BM * Tt; idx += RNT)
    s_tok[idx] = tokens[b0 * Tt + idx];

  for (int idx = tid; idx < BM * Uu; idx += RNT) {
    int r = idx >> 8, c = idx & 255;
    int off = (c >> 5) * HCH + (((c >> 3) & 3) * 8 + r) * 8 + (c & 7);
    s_h0[off] = (__bf16)ldf<ISBF>(h0g, (b0 + r) * Uu + c);
    s_h1[off] = (__bf16)ldf<ISBF>(h0g, Bb * Uu + (b0 + r) * Uu + c);
  }
  __syncthreads();

  // ---- fused U-producer (R9-proven mapping; waves 0..7 only) -------------
  if (wv < 8) {
    bf16x8 fX[2][4];
    float b0v[2];
    #pragma unroll
    for (int e = 0; e < 2; ++e) {
      const int col = wv * 32 + e * 16 + m;
      b0v[e] = ldf<ISBF>(bias, col);
      #pragma unroll
      for (int s = 0; s < 4; ++s) {
        bf16x8 tr;
        #pragma unroll
        for (int j = 0; j < 8; ++j) {
          int k = s * 32 + kc * 8 + j;
          tr[j] = (k < Ee) ? (__bf16)ldf<ISBF>(Wx0, k * Uu + col) : (__bf16)0.f;
        }
        fX[e][s] = tr;
      }
    }
    const int tid32p = (wv >> 1) * 32 + (kc & 1) * 16 + m;
    __bf16* Ustore = U + (size_t)tid32p * 16 + (wv & 1) * 8;
    for (int tc = 0; tc < 10; ++tc) {
      const int T0 = tc * 8;
      // gather/compute in pairs of tokens (32 regs in flight, fits the cap)
      #pragma unroll
      for (int half = 0; half < 2; ++half) {
        bf16x8 xa[2][4];
        #pragma unroll
        for (int q = 0; q < 2; ++q) {
          const int mt = half * 2 + q;
          const int tok = s_tok[(m & 7) * Tt + T0 + mt * 2 + (m >> 3)];
          #pragma unroll
          for (int s = 0; s < 4; ++s) {
            const int k0 = s * 32 + kc * 8;
            if (k0 + 8 <= Ee) {
              if constexpr (ISBF) {
                xa[q][s] = *(const bf16x8*)((const __bf16*)emb + tok * Ee + k0);
              } else {
                f32x4 lo = *(const f32x4*)((const float*)emb + tok * Ee + k0);
                f32x4 hi = *(const f32x4*)((const float*)emb + tok * Ee + k0 + 4);
                #pragma unroll
                for (int j = 0; j < 4; ++j) { xa[q][s][j] = (__bf16)lo[j]; xa[q][s][4 + j] = (__bf16)hi[j]; }
              }
            } else if (k0 < Ee) {       // k0==96: one vector load of k=96..99
              if constexpr (ISBF) {
                bf16x4 t4 = *(const bf16x4*)((const __bf16*)emb + tok * Ee + k0);
                #pragma unroll
                for (int j = 0; j < 4; ++j) { xa[q][s][j] = t4[j]; xa[q][s][4 + j] = (__bf16)0.f; }
              } else {
                f32x4 t4 = *(const f32x4*)((const float*)emb + tok * Ee + k0);
                #pragma unroll
                for (int j = 0; j < 4; ++j) { xa[q][s][j] = (__bf16)t4[j]; xa[q][s][4 + j] = (__bf16)0.f; }
              }
            } else {                    // k0 >= 100 (kc-dependent): all zero
              #pragma unroll
              for (int j = 0; j < 8; ++j) xa[q][s][j] = (__bf16)0.f;
            }
          }
        }
        #pragma unroll
        for (int q = 0; q < 2; ++q) {
          const int mt = half * 2 + q;
          f32x4 a0 = {b0v[0], b0v[0], b0v[0], b0v[0]};
          f32x4 a1 = {b0v[1], b0v[1], b0v[1], b0v[1]};
          #pragma unroll
          for (int s = 0; s < 4; ++s) {
            a0 = MFMA16(xa[q][s], fX[0][s], a0);
            a1 = MFMA16(xa[q][s], fX[1][s], a1);
          }
          bf16x8 pk;
          #pragma unroll
          for (int i = 0; i < 4; ++i) { pk[i] = (__bf16)a0[i]; pk[4 + i] = (__bf16)a1[i]; }
          const int t_l = T0 + mt * 2 + (kc >> 1);
          *(bf16x8*)(Ustore + (size_t)(t_l * 256 + rb) * 2048) = pk;
        }
      }
    }
  }

  // ---- weight B-frags: ONE 16-col tile (tw=wv) x 3 mats x 8 chunks -------
  // UNCONSTRAINED: allocator places these in AGPR (AV-class MFMA operands).
  const int tw = wv;                     // wave's output tile: cols tw*16+m
  bf16x8 fWh0[8], fWx1f[8], fWh1[8];
  {
    const int col = tw * 16 + m;
    #pragma unroll
    for (int s = 0; s < 8; ++s) {
      const int kb = s * 32 + kc * 8;
      bf16x8 t0, t1, t2;
      #pragma unroll
      for (int j = 0; j < 8; ++j) {
        t0[j] = (__bf16)ldf<ISBF>(Wh,  (kb + j) * Uu + col);
        t1[j] = (__bf16)ldf<ISBF>(Wx1, (kb + j) * Uu + col);
        t2[j] = (__bf16)ldf<ISBF>(Wh,  Uu * Uu + (kb + j) * Uu + col);
      }
      fWh0[s] = t0; fWx1f[s] = t1; fWh1[s] = t2;
    }
  }

  const float b1s = ldf<ISBF>(bias, Uu + tw * 16 + m);

  // u fetch: lane needs u(br=(kc&1)*4+i, col=tw*16+m), i=0..3 -> bf16x4 at
  // O = (col>>6)*512+(br>>2)*256+(col&15)*16+((col>>5)&1)*8+((col>>4)&1)*4+i
  const int O0u = (tw >> 2) * 512 + (kc & 1) * 256 + m * 16 +
                  ((tw >> 1) & 1) * 8 + (tw & 1) * 4;
  const __bf16* Ubase = U + (size_t)rb * 2048 + O0u;

  // write offset: rows r0=(kc&1)*4 (+i), col tw*16+m; hf picks h0 vs h1 dest
  const int woff = (tw >> 1) * 256 +
                   ((((tw * 2) + (m >> 3)) & 3) * 8 + (kc & 1) * 4) * 8 + (m & 7);

  __syncthreads();   // drain U stores (vmcnt) + LDS staging

  bf16x4 u0 = *(const bf16x4*)(Ubase);   // u(0)

  // ---- prologue: h0_new(0) = tanh(u(0) + h0_init@Wh0) -> s_h0[1] ----
  {
    f32x4 d = {(float)u0[0], (float)u0[1], (float)u0[2], (float)u0[3]};
    const __bf16* ab = (mh ? s_h1 : s_h0) + au2;   // packed A (rows8-15 junk)
    #pragma unroll
    for (int s = 0; s < 8; ++s) {
      bf16x8 a = *(const bf16x8*)(ab + s * HCH);
      d = MFMA16(a, fWh0[s], d);
    }
    u0 = *(const bf16x4*)(Ubase + (size_t)1 * 256 * 2048);  // prefetch u(1)
    if (hf == 0) {                        // lower half holds real rows 0-7
      __bf16* wp = s_h0 + HB + woff;
      #pragma unroll
      for (int ii = 0; ii < 4; ++ii) wp[ii * 8] = (__bf16)fast_tanh(d[ii]);
    }
    barrier_lds();
  }

  for (int t = 0; t < Tt; ++t) {
    const int p = t & 1, pn = p ^ 1;
    int tf = (t + 2 < Tt) ? t + 2 : Tt - 1;
    bf16x4 un = *(const bf16x4*)(Ubase + (size_t)tf * 256 * 2048);

    // packed A: rows0-7 = h0n(t) from s_h0[pn], rows8-15 = h1(t) from s_h1[p]
    const __bf16* ab = (mh ? (s_h1 + p * HB) : (s_h0 + pn * HB)) + au2;

    // 3 chains, one A-read each round:
    //  accX rows0-7 = h0n@Wx1 ; accH rows8-15 = h1@Wh1 ; accD rows0-7 = u+h0n@Wh0
    f32x4 accX = {0.f, 0.f, 0.f, 0.f}, accH = {0.f, 0.f, 0.f, 0.f};
    f32x4 accD = {(float)u0[0], (float)u0[1], (float)u0[2], (float)u0[3]};
    #pragma unroll
    for (int s = 0; s < 8; ++s) {
      bf16x8 a = *(const bf16x8*)(ab + s * HCH);
      accX = MFMA16(a, fWx1f[s], accX);
      accH = MFMA16(a, fWh1[s], accH);
      accD = MFMA16(a, fWh0[s], accD);
    }

    // cross-half combine: one swap delivers accH.hi->lower (h1 piece) AND
    // accD.lo->upper (h0 piece). Lower half writes h1_new, upper writes h0.
    __bf16* wpw = (hf ? (s_h0 + p * HB) : (s_h1 + pn * HB)) + woff;
    #pragma unroll
    for (int i = 0; i < 4; ++i) {
      float hx = accH[i], dx = accD[i];
      if (forma) asm volatile("v_permlane32_swap_b32 %0, %1" : "+v"(hx), "+v"(dx));
      else       asm volatile("v_permlane32_swap_b32 %0, %1" : "+v"(dx), "+v"(hx));
      // post: hx.upperlanes = accD.lo (u+h0n@Wh0), dx.lowerlanes = accH.hi
      float v = hf ? hx : (accX[i] + dx + b1s);
      wpw[i * 8] = (__bf16)fast_tanh(v);
    }
    u0 = un;
    barrier_lds();
  }

  // ---- epilogue: sigmoid(h1_new(79) @ Wo + bo); lives in s_h1[0] ----
  if (tid < 256) {
    const int r = tid >> 5, q = tid & 31;
    const __bf16* hp = s_h1 + (q >> 2) * HCH + ((q & 3) * 8 + r) * 8;
    bf16x8 hv = *(const bf16x8*)hp;
    float part = 0.f;
    #pragma unroll
    for (int j = 0; j < 8; ++j) part += (float)hv[j] * ldf<ISBF>(Wo, q * 8 + j);
    #pragma unroll
    for (int o = 16; o >= 1; o >>= 1) part += __shfl_down(part, o, 32);
    if (q == 0) {
      float z = part + ldf<ISBF>(bo, 0);
      float sg = 1.f / (1.f + __expf(-z));
      if constexpr (ISBF) ((__bf16*)out)[b0 + r] = (__bf16)sg;
      else                ((float*)out)[b0 + r]  = sg;
    }
  }
}

extern "C" void kernel_launch(void* const* d_in, const int* in_sizes, int n_in,
                              void* d_out, int out_size, void* d_ws, size_t ws_size,
                              hipStream_t stream) {
  const int*  tokens = (const int*)d_in[0];
  const void* emb = d_in[1];
  const void* Wx0 = d_in[2];
  const void* Wx1 = d_in[3];
  const void* Wh  = d_in[4];
  const void* b   = d_in[5];
  const void* h0  = d_in[6];
  const void* Wo  = d_in[7];
  const void* bo  = d_in[8];

  __bf16* U = (__bf16*)((char*)d_ws + 256);
  const size_t needU = 256 + (size_t)Tt * 256 * 2048 * sizeof(__bf16);  // ~84 MB
  if (ws_size < needU) return;

  rnn_kernel<true ><<<dim3(Bb / BM), dim3(RNT), 0, stream>>>(
      tokens, emb, Wx0, Wx1, Wh, b, h0, Wo, bo, U, d_out);
  rnn_kernel<false><<<dim3(Bb / BM), dim3(RNT), 0, stream>>>(
      tokens, emb, Wx0, Wx1, Wh, b, h0, Wo, bo, U, d_out);
}

// Round 6
// 259.986 us; speedup vs baseline: 1.2254x; 1.2254x over previous
//
#include <hip/hip_runtime.h>
#include <hip/hip_bf16.h>

typedef __bf16 bf16x8 __attribute__((ext_vector_type(8)));
typedef __bf16 bf16x4 __attribute__((ext_vector_type(4)));
typedef float  f32x4  __attribute__((ext_vector_type(4)));

#define MFMA16(a,b,c) __builtin_amdgcn_mfma_f32_16x16x32_bf16((a),(b),(c),0,0,0)

// Opaque pin: forces fragments register-resident (R0-proven at 512thr/2waves).
#define PIN8(v8) do { f32x4 _t = __builtin_bit_cast(f32x4, (v8)); \
                      asm volatile("" : "+v"(_t)); \
                      (v8) = __builtin_bit_cast(bf16x8, _t); } while (0)

// LDS-only barrier: leaves the global u-prefetch vmcnt outstanding.
__device__ __forceinline__ void barrier_lds() {
  asm volatile("s_waitcnt lgkmcnt(0)\n\ts_barrier" ::: "memory");
}

constexpr int Bb = 2048, Tt = 80, Ee = 100, Uu = 256;
constexpr int BM = 8;          // batch rows per block
constexpr int RNT = 512;       // 8 waves, 2 waves/SIMD (only feasible occup.)
constexpr int HCH = 256;       // elems per k-chunk (32 k x 8 rows)
constexpr int HB = 8 * HCH;    // one h buffer

template<bool ISBF>
__device__ __forceinline__ float ldf(const void* p, int i) {
  if constexpr (ISBF) return (float)((const __bf16*)p)[i];
  else                return ((const float*)p)[i];
}

__device__ __forceinline__ float fast_tanh(float x) {
  float e = __expf(2.f * x);
  return 1.f - 2.f / (e + 1.f);
}

// In-kernel dtype detect: f32 storage -> low 16-bit halves decode as bf16
// with wild exponents ~84% of the time; genuine bf16 N(0,1/16) never does.
__device__ __forceinline__ bool detect_bf16(const void* wh) {
  const unsigned short* u = (const unsigned short*)wh;
  int c = 0;
  const int lane = threadIdx.x & 63;
  #pragma unroll
  for (int r = 0; r < 4; ++r) {
    unsigned short h = u[2 * (lane + 64 * r)];
    int ex = (h >> 7) & 0xFF;
    if (ex >= 135 || (ex >= 1 && ex <= 95)) c++;
  }
  #pragma unroll
  for (int o = 32; o >= 1; o >>= 1) c += __shfl_down(c, o, 64);
  return __shfl(c, 0, 64) < 64;
}

// ---------------- persistent 2-layer RNN with fused U-production -----------
// R6 = R0 8-wave base (193us, proven; 16-wave is structurally infeasible:
// 16 tiles x 96 weight regs = 1536 regs/block > what 4 waves/SIMD leaves)
// + PACKED-A from R5 (verified correct there): A rows0-7 = h0n, rows8-15 =
// h1, so ONE ds_read feeds all 3 chains -> scan A-reads 16/wave -> 8/wave
// (128 -> 64 per CU-step). Combine via runtime-probed permlane32_swap;
// full-wave tail: lower half writes h1_new (both tiles), upper writes h0.
template<bool ISBF>
__launch_bounds__(RNT, 2)
__global__ void rnn_kernel(const int* __restrict__ tokens,
                           const void* __restrict__ emb,
                           const void* __restrict__ Wx0,
                           const void* __restrict__ Wx1,
                           const void* __restrict__ Wh,
                           const void* __restrict__ bias,
                           const void* __restrict__ h0g,
                           const void* __restrict__ Wo,
                           const void* __restrict__ bo,
                           __bf16* __restrict__ U,
                           void* __restrict__ out) {
  if (detect_bf16(Wh) != ISBF) return;   // wrong-dtype instantiation exits

  __shared__ __align__(16) __bf16 s_h0[2 * HB];
  __shared__ __align__(16) __bf16 s_h1[2 * HB];
  __shared__ int s_tok[BM * Tt];

  const int tid = threadIdx.x, lane = tid & 63, wv = tid >> 6;  // wv 0..7
  const int m = lane & 15, kc = lane >> 4, hf = lane >> 5;
  const int mh = (m >> 3) & 1;           // packed-A source: 0=h0n, 1=h1
  const int rb = blockIdx.x, b0 = rb * BM;
  const int au2 = (kc * 8 + (m & 7)) * 8;  // packed A-read (row m&7, ksub kc)

  // permlane32_swap operand-semantics probe (wave-uniform, 2 instrs):
  // form A: vdst.upper <-> vsrc.lower ; form B: vdst.lower <-> vsrc.upper.
  int pv = lane, qv = 64 + lane;
  asm volatile("v_permlane32_swap_b32 %0, %1" : "+v"(pv), "+v"(qv));
  const bool forma = (__shfl(pv, 0, 64) == 0);  // lane0 pv unchanged => A

  for (int idx = tid; idx < BM * Tt; idx += RNT)
    s_tok[idx] = tokens[b0 * Tt + idx];

  for (int idx = tid; idx < BM * Uu; idx += RNT) {
    int r = idx >> 8, c = idx & 255;
    int off = (c >> 5) * HCH + (((c >> 3) & 3) * 8 + r) * 8 + (c & 7);
    s_h0[off] = (__bf16)ldf<ISBF>(h0g, (b0 + r) * Uu + c);
    s_h1[off] = (__bf16)ldf<ISBF>(h0g, Bb * Uu + (b0 + r) * Uu + c);
  }
  __syncthreads();

  // ---- fused U-producer (R9-proven mapping; pipelined gathers) -----------
  {
    bf16x8 fX[2][4];
    float b0v[2];
    #pragma unroll
    for (int e = 0; e < 2; ++e) {
      const int col = wv * 32 + e * 16 + m;
      b0v[e] = ldf<ISBF>(bias, col);
      #pragma unroll
      for (int s = 0; s < 4; ++s) {
        bf16x8 tr;
        #pragma unroll
        for (int j = 0; j < 8; ++j) {
          int k = s * 32 + kc * 8 + j;
          tr[j] = (k < Ee) ? (__bf16)ldf<ISBF>(Wx0, k * Uu + col) : (__bf16)0.f;
        }
        fX[e][s] = tr;
      }
    }
    const int tid32p = (wv >> 1) * 32 + (kc & 1) * 16 + m;
    __bf16* Ustore = U + (size_t)tid32p * 16 + (wv & 1) * 8;
    for (int tc = 0; tc < 10; ++tc) {
      const int T0 = tc * 8;
      // phase 1: all 16 gathers in flight (no MFMA between them)
      bf16x8 xa[4][4];
      #pragma unroll
      for (int mt = 0; mt < 4; ++mt) {
        const int tok = s_tok[(m & 7) * Tt + T0 + mt * 2 + (m >> 3)];
        #pragma unroll
        for (int s = 0; s < 4; ++s) {
          const int k0 = s * 32 + kc * 8;
          if (k0 + 8 <= Ee) {
            if constexpr (ISBF) {
              xa[mt][s] = *(const bf16x8*)((const __bf16*)emb + tok * Ee + k0);
            } else {
              f32x4 lo = *(const f32x4*)((const float*)emb + tok * Ee + k0);
              f32x4 hi = *(const f32x4*)((const float*)emb + tok * Ee + k0 + 4);
              #pragma unroll
              for (int j = 0; j < 4; ++j) { xa[mt][s][j] = (__bf16)lo[j]; xa[mt][s][4 + j] = (__bf16)hi[j]; }
            }
          } else if (k0 < Ee) {       // k0==96: one vector load of k=96..99
            if constexpr (ISBF) {
              bf16x4 t4 = *(const bf16x4*)((const __bf16*)emb + tok * Ee + k0);
              #pragma unroll
              for (int j = 0; j < 4; ++j) { xa[mt][s][j] = t4[j]; xa[mt][s][4 + j] = (__bf16)0.f; }
            } else {
              f32x4 t4 = *(const f32x4*)((const float*)emb + tok * Ee + k0);
              #pragma unroll
              for (int j = 0; j < 4; ++j) { xa[mt][s][j] = (__bf16)t4[j]; xa[mt][s][4 + j] = (__bf16)0.f; }
            }
          } else {                    // k0 >= 100 (kc-dependent): all zero
            #pragma unroll
            for (int j = 0; j < 8; ++j) xa[mt][s][j] = (__bf16)0.f;
          }
        }
      }
      // phase 2: MFMA chains + packed stores
      #pragma unroll
      for (int mt = 0; mt < 4; ++mt) {
        f32x4 a0 = {b0v[0], b0v[0], b0v[0], b0v[0]};
        f32x4 a1 = {b0v[1], b0v[1], b0v[1], b0v[1]};
        #pragma unroll
        for (int s = 0; s < 4; ++s) {
          a0 = MFMA16(xa[mt][s], fX[0][s], a0);
          a1 = MFMA16(xa[mt][s], fX[1][s], a1);
        }
        bf16x8 pk;
        #pragma unroll
        for (int i = 0; i < 4; ++i) { pk[i] = (__bf16)a0[i]; pk[4 + i] = (__bf16)a1[i]; }
        const int t_l = T0 + mt * 2 + (kc >> 1);
        *(bf16x8*)(Ustore + (size_t)(t_l * 256 + rb) * 2048) = pk;
      }
    }
  }

  // ---- pinned weight B-frags: 2 tiles x 3 matrices x 8 chunks ------------
  bf16x8 fWh0[2][8], fWx1f[2][8], fWh1[2][8];
  #pragma unroll
  for (int e = 0; e < 2; ++e) {
    const int col = wv * 32 + e * 16 + m;
    #pragma unroll
    for (int s = 0; s < 8; ++s) {
      const int kb = s * 32 + kc * 8;
      bf16x8 t0, t1, t2;
      #pragma unroll
      for (int j = 0; j < 8; ++j) {
        t0[j] = (__bf16)ldf<ISBF>(Wh,  (kb + j) * Uu + col);
        t1[j] = (__bf16)ldf<ISBF>(Wx1, (kb + j) * Uu + col);
        t2[j] = (__bf16)ldf<ISBF>(Wh,  Uu * Uu + (kb + j) * Uu + col);
      }
      fWh0[e][s] = t0; fWx1f[e][s] = t1; fWh1[e][s] = t2;
    }
  }
  #pragma unroll
  for (int e = 0; e < 2; ++e) {
    #pragma unroll
    for (int s = 0; s < 8; ++s) {
      PIN8(fWh0[e][s]); PIN8(fWx1f[e][s]); PIN8(fWh1[e][s]);
    }
  }
  // layer-1 bias for BOTH tiles (lower half writes h1_new for both):
  float b1v[2];
  b1v[0] = ldf<ISBF>(bias, Uu + wv * 32 + m);
  b1v[1] = ldf<ISBF>(bias, Uu + wv * 32 + 16 + m);

  // u fetch: lane reads tid32 = (wv>>1)*32 + (kc&1)*16 + m, slots (wv&1)*8..+7
  // u0[0..3] = tile0 rows (kc&1)*4+i ; u0[4..7] = tile1 rows. (R0-proven.)
  const int tid32u = (wv >> 1) * 32 + ((kc & 1) * 16) + m;
  const __bf16* Ubase = U + (size_t)tid32u * 16 + (wv & 1) * 8 + (size_t)rb * 2048;

  // write offsets per tile e: col = (wv*2+e)*16 + m, rows (kc&1)*4 + ii
  // off(col,r) = (col>>5)*HCH + (((col>>3)&3)*8 + r)*8 + (col&7)   [staging map]
  int woffe[2];
  #pragma unroll
  for (int e = 0; e < 2; ++e) {
    const int col = (wv * 2 + e) * 16 + m;
    woffe[e] = (col >> 5) * HCH + ((((col >> 3) & 3) * 8) + (kc & 1) * 4) * 8 + (col & 7);
  }

  __syncthreads();   // drain U stores (vmcnt) + LDS staging

  bf16x8 u0 = *(const bf16x8*)(Ubase);   // u(0)

  // ---- prologue: h0_new(0) = tanh(u(0) + h0_init@Wh0) -> s_h0[1] ----
  {
    f32x4 d0 = {(float)u0[0], (float)u0[1], (float)u0[2], (float)u0[3]};
    f32x4 d1 = {(float)u0[4], (float)u0[5], (float)u0[6], (float)u0[7]};
    const __bf16* ab = (mh ? s_h1 : s_h0) + au2;   // packed A (h1 rows unused)
    #pragma unroll
    for (int s = 0; s < 8; ++s) {
      bf16x8 a = *(const bf16x8*)(ab + s * HCH);
      d0 = MFMA16(a, fWh0[0][s], d0);
      d1 = MFMA16(a, fWh0[1][s], d1);
    }
    u0 = *(const bf16x8*)(Ubase + (size_t)1 * 256 * 2048);  // prefetch u(1)
    if (hf == 0) {                        // lower half holds real rows 0-7
      #pragma unroll
      for (int ii = 0; ii < 4; ++ii) {
        (s_h0 + HB + woffe[0])[ii * 8] = (__bf16)fast_tanh(d0[ii]);
        (s_h0 + HB + woffe[1])[ii * 8] = (__bf16)fast_tanh(d1[ii]);
      }
    }
    barrier_lds();
  }

  for (int t = 0; t < Tt; ++t) {
    const int p = t & 1, pn = p ^ 1;
    int tf = (t + 2 < Tt) ? t + 2 : Tt - 1;
    bf16x8 un = *(const bf16x8*)(Ubase + (size_t)tf * 256 * 2048);

    // packed A: rows0-7 = h0n(t) from s_h0[pn], rows8-15 = h1(t) from s_h1[p]
    const __bf16* ab = (mh ? (s_h1 + p * HB) : (s_h0 + pn * HB)) + au2;

    // 6 chains (3 per tile), ONE A-read per k-chunk:
    //  aX rows0-7 = h0n@Wx1 ; aH rows8-15 = h1@Wh1 ; aD rows0-7 = u+h0n@Wh0
    f32x4 aX0 = {0.f,0.f,0.f,0.f}, aH0 = {0.f,0.f,0.f,0.f};
    f32x4 aX1 = {0.f,0.f,0.f,0.f}, aH1 = {0.f,0.f,0.f,0.f};
    f32x4 aD0 = {(float)u0[0], (float)u0[1], (float)u0[2], (float)u0[3]};
    f32x4 aD1 = {(float)u0[4], (float)u0[5], (float)u0[6], (float)u0[7]};
    #pragma unroll
    for (int s = 0; s < 8; ++s) {
      bf16x8 a = *(const bf16x8*)(ab + s * HCH);
      aX0 = MFMA16(a, fWx1f[0][s], aX0);
      aD0 = MFMA16(a, fWh0[0][s], aD0);
      aH0 = MFMA16(a, fWh1[0][s], aH0);
      aX1 = MFMA16(a, fWx1f[1][s], aX1);
      aD1 = MFMA16(a, fWh0[1][s], aD1);
      aH1 = MFMA16(a, fWh1[1][s], aH1);
    }

    // cross-half combine per tile: one swap delivers aH.hi -> lower lanes
    // (h1 piece) AND aD.lo -> upper lanes (h0 piece). Lower half writes
    // h1_new (both tiles), upper half writes h0_next (both tiles).
    __bf16* wb = hf ? (s_h0 + p * HB) : (s_h1 + pn * HB);
    __bf16* wpw0 = wb + woffe[0];
    __bf16* wpw1 = wb + woffe[1];
    #pragma unroll
    for (int i = 0; i < 4; ++i) {
      float hx0 = aH0[i], dx0 = aD0[i];
      float hx1 = aH1[i], dx1 = aD1[i];
      if (forma) {
        asm volatile("v_permlane32_swap_b32 %0, %1" : "+v"(hx0), "+v"(dx0));
        asm volatile("v_permlane32_swap_b32 %0, %1" : "+v"(hx1), "+v"(dx1));
      } else {
        asm volatile("v_permlane32_swap_b32 %0, %1" : "+v"(dx0), "+v"(hx0));
        asm volatile("v_permlane32_swap_b32 %0, %1" : "+v"(dx1), "+v"(hx1));
      }
      // post: hx.upperlanes = aD.lo (u+h0n@Wh0), dx.lowerlanes = aH.hi
      float v0 = hf ? hx0 : (aX0[i] + dx0 + b1v[0]);
      float v1 = hf ? hx1 : (aX1[i] + dx1 + b1v[1]);
      wpw0[i * 8] = (__bf16)fast_tanh(v0);
      wpw1[i * 8] = (__bf16)fast_tanh(v1);
    }
    u0 = un;
    barrier_lds();
  }

  // ---- epilogue: sigmoid(h1_new(79) @ Wo + bo); lives in s_h1[0] ----
  if (tid < 256) {
    const int r = tid >> 5, q = tid & 31;
    const __bf16* hp = s_h1 + (q >> 2) * HCH + ((q & 3) * 8 + r) * 8;
    bf16x8 hv = *(const bf16x8*)hp;
    float part = 0.f;
    #pragma unroll
    for (int j = 0; j < 8; ++j) part += (float)hv[j] * ldf<ISBF>(Wo, q * 8 + j);
    #pragma unroll
    for (int o = 16; o >= 1; o >>= 1) part += __shfl_down(part, o, 32);
    if (q == 0) {
      float z = part + ldf<ISBF>(bo, 0);
      float sg = 1.f / (1.f + __expf(-z));
      if constexpr (ISBF) ((__bf16*)out)[b0 + r] = (__bf16)sg;
      else                ((float*)out)[b0 + r]  = sg;
    }
  }
}

extern "C" void kernel_launch(void* const* d_in, const int* in_sizes, int n_in,
                              void* d_out, int out_size, void* d_ws, size_t ws_size,
                              hipStream_t stream) {
  const int*  tokens = (const int*)d_in[0];
  const void* emb = d_in[1];
  const void* Wx0 = d_in[2];
  const void* Wx1 = d_in[3];
  const void* Wh  = d_in[4];
  const void* b   = d_in[5];
  const void* h0  = d_in[6];
  const void* Wo  = d_in[7];
  const void* bo  = d_in[8];

  __bf16* U = (__bf16*)((char*)d_ws + 256);
  const size_t needU = 256 + (size_t)Tt * 256 * 2048 * sizeof(__bf16);  // ~84 MB
  if (ws_size < needU) return;

  rnn_kernel<true ><<<dim3(Bb / BM), dim3(RNT), 0, stream>>>(
      tokens, emb, Wx0, Wx1, Wh, b, h0, Wo, bo, U, d_out);
  rnn_kernel<false><<<dim3(Bb / BM), dim3(RNT), 0, stream>>>(
      tokens, emb, Wx0, Wx1, Wh, b, h0, Wo, bo, U, d_out);
}

// Round 7
// 238.182 us; speedup vs baseline: 1.3376x; 1.0915x over previous
//
#include <hip/hip_runtime.h>
#include <hip/hip_bf16.h>

typedef __bf16 bf16x8 __attribute__((ext_vector_type(8)));
typedef __bf16 bf16x4 __attribute__((ext_vector_type(4)));
typedef float  f32x4  __attribute__((ext_vector_type(4)));

#define MFMA16(a,b,c) __builtin_amdgcn_mfma_f32_16x16x32_bf16((a),(b),(c),0,0,0)

// Opaque pin: forces fragments register-resident (not rematerializable).
#define PIN8(v8) do { f32x4 _t = __builtin_bit_cast(f32x4, (v8)); \
                      asm volatile("" : "+v"(_t)); \
                      (v8) = __builtin_bit_cast(bf16x8, _t); } while (0)

// LDS-only barrier: leaves the global u-prefetch vmcnt outstanding.
__device__ __forceinline__ void barrier_lds() {
  asm volatile("s_waitcnt lgkmcnt(0)\n\ts_barrier" ::: "memory");
}

constexpr int Bb = 2048, Tt = 80, Ee = 100, Uu = 256;
constexpr int BM = 8;          // batch rows per block
constexpr int RNT = 512;       // 8 waves
constexpr int HCH = 256;       // elems per k-chunk (32 k x 8 rows)
constexpr int HB = 8 * HCH;    // one h buffer

template<bool ISBF>
__device__ __forceinline__ float ldf(const void* p, int i) {
  if constexpr (ISBF) return (float)((const __bf16*)p)[i];
  else                return ((const float*)p)[i];
}

__device__ __forceinline__ float fast_tanh(float x) {
  float e = __expf(2.f * x);
  return 1.f - 2.f / (e + 1.f);
}

// In-kernel dtype detect: f32 storage -> low 16-bit halves decode as bf16
// with wild exponents ~84% of the time; genuine bf16 N(0,1/16) never does.
__device__ __forceinline__ bool detect_bf16(const void* wh) {
  const unsigned short* u = (const unsigned short*)wh;
  int c = 0;
  const int lane = threadIdx.x & 63;
  #pragma unroll
  for (int r = 0; r < 4; ++r) {
    unsigned short h = u[2 * (lane + 64 * r)];
    int ex = (h >> 7) & 0xFF;
    if (ex >= 135 || (ex >= 1 && ex <= 95)) c++;
  }
  #pragma unroll
  for (int o = 32; o >= 1; o >>= 1) c += __shfl_down(c, o, 64);
  return __shfl(c, 0, 64) < 64;
}

// ---------------- persistent 2-layer RNN with fused U-production -----------
// R7 = exact revert to R1 (session best, 192-194us) + s_setprio around the
// MFMA loop. Six rounds of restructures (ILP prefetch, 16-wave occupancy,
// AGPR pinning, packed-A read-halving) were all null or negative; counters
// show no spill, no scan conflicts, no copy-VALU -- the ~60% idle is 2-wave
// lockstep latency that the 192-reg weight working set makes irreducible.
template<bool ISBF>
__launch_bounds__(RNT, 2)
__global__ void rnn_kernel(const int* __restrict__ tokens,
                           const void* __restrict__ emb,
                           const void* __restrict__ Wx0,
                           const void* __restrict__ Wx1,
                           const void* __restrict__ Wh,
                           const void* __restrict__ bias,
                           const void* __restrict__ h0g,
                           const void* __restrict__ Wo,
                           const void* __restrict__ bo,
                           __bf16* __restrict__ U,
                           void* __restrict__ out) {
  if (detect_bf16(Wh) != ISBF) return;   // wrong-dtype instantiation exits

  __shared__ __align__(16) __bf16 s_h0[2 * HB];
  __shared__ __align__(16) __bf16 s_h1[2 * HB];
  __shared__ int s_tok[BM * Tt];

  const int tid = threadIdx.x, lane = tid & 63, wv = tid >> 6;  // wv 0..7
  const int m = lane & 15, kc = lane >> 4, hf = lane >> 5;
  const int rb = blockIdx.x, b0 = rb * BM;
  const int au = (kc * 8 + (m & 7)) * 8;   // A-read; lanes m>=8 broadcast row m-8

  for (int idx = tid; idx < BM * Tt; idx += RNT)
    s_tok[idx] = tokens[b0 * Tt + idx];

  for (int idx = tid; idx < BM * Uu; idx += RNT) {
    int r = idx >> 8, c = idx & 255;
    int off = (c >> 5) * HCH + (((c >> 3) & 3) * 8 + r) * 8 + (c & 7);
    s_h0[off] = (__bf16)ldf<ISBF>(h0g, (b0 + r) * Uu + c);
    s_h1[off] = (__bf16)ldf<ISBF>(h0g, Bb * Uu + (b0 + r) * Uu + c);
  }
  __syncthreads();

  // ---- fused U-producer (R9-proven mapping; pipelined gathers) -----------
  {
    bf16x8 fX[2][4];
    float b0v[2];
    #pragma unroll
    for (int e = 0; e < 2; ++e) {
      const int col = wv * 32 + e * 16 + m;
      b0v[e] = ldf<ISBF>(bias, col);
      #pragma unroll
      for (int s = 0; s < 4; ++s) {
        bf16x8 tr;
        #pragma unroll
        for (int j = 0; j < 8; ++j) {
          int k = s * 32 + kc * 8 + j;
          tr[j] = (k < Ee) ? (__bf16)ldf<ISBF>(Wx0, k * Uu + col) : (__bf16)0.f;
        }
        fX[e][s] = tr;
      }
    }
    const int tid32p = (wv >> 1) * 32 + (kc & 1) * 16 + m;
    __bf16* Ustore = U + (size_t)tid32p * 16 + (wv & 1) * 8;
    for (int tc = 0; tc < 10; ++tc) {
      const int T0 = tc * 8;
      // phase 1: all 16 gathers in flight (no MFMA between them)
      bf16x8 xa[4][4];
      #pragma unroll
      for (int mt = 0; mt < 4; ++mt) {
        const int tok = s_tok[(m & 7) * Tt + T0 + mt * 2 + (m >> 3)];
        #pragma unroll
        for (int s = 0; s < 4; ++s) {
          const int k0 = s * 32 + kc * 8;
          if (k0 + 8 <= Ee) {
            if constexpr (ISBF) {
              xa[mt][s] = *(const bf16x8*)((const __bf16*)emb + tok * Ee + k0);
            } else {
              f32x4 lo = *(const f32x4*)((const float*)emb + tok * Ee + k0);
              f32x4 hi = *(const f32x4*)((const float*)emb + tok * Ee + k0 + 4);
              #pragma unroll
              for (int j = 0; j < 4; ++j) { xa[mt][s][j] = (__bf16)lo[j]; xa[mt][s][4 + j] = (__bf16)hi[j]; }
            }
          } else if (k0 < Ee) {       // k0==96: one vector load of k=96..99
            if constexpr (ISBF) {
              bf16x4 t4 = *(const bf16x4*)((const __bf16*)emb + tok * Ee + k0);
              #pragma unroll
              for (int j = 0; j < 4; ++j) { xa[mt][s][j] = t4[j]; xa[mt][s][4 + j] = (__bf16)0.f; }
            } else {
              f32x4 t4 = *(const f32x4*)((const float*)emb + tok * Ee + k0);
              #pragma unroll
              for (int j = 0; j < 4; ++j) { xa[mt][s][j] = (__bf16)t4[j]; xa[mt][s][4 + j] = (__bf16)0.f; }
            }
          } else {                    // k0 >= 100 (kc-dependent): all zero
            #pragma unroll
            for (int j = 0; j < 8; ++j) xa[mt][s][j] = (__bf16)0.f;
          }
        }
      }
      // phase 2: MFMA chains + packed stores
      #pragma unroll
      for (int mt = 0; mt < 4; ++mt) {
        f32x4 a0 = {b0v[0], b0v[0], b0v[0], b0v[0]};
        f32x4 a1 = {b0v[1], b0v[1], b0v[1], b0v[1]};
        #pragma unroll
        for (int s = 0; s < 4; ++s) {
          a0 = MFMA16(xa[mt][s], fX[0][s], a0);
          a1 = MFMA16(xa[mt][s], fX[1][s], a1);
        }
        bf16x8 pk;
        #pragma unroll
        for (int i = 0; i < 4; ++i) { pk[i] = (__bf16)a0[i]; pk[4 + i] = (__bf16)a1[i]; }
        const int t_l = T0 + mt * 2 + (kc >> 1);
        *(bf16x8*)(Ustore + (size_t)(t_l * 256 + rb) * 2048) = pk;
      }
    }
  }

  // ---- pinned weight B-frags: 2 tiles x 3 matrices x 8 chunks ------------
  bf16x8 fWh0[2][8], fWx1f[2][8], fWh1[2][8];
  #pragma unroll
  for (int e = 0; e < 2; ++e) {
    const int col = wv * 32 + e * 16 + m;
    #pragma unroll
    for (int s = 0; s < 8; ++s) {
      const int kb = s * 32 + kc * 8;
      bf16x8 t0, t1, t2;
      #pragma unroll
      for (int j = 0; j < 8; ++j) {
        t0[j] = (__bf16)ldf<ISBF>(Wh,  (kb + j) * Uu + col);
        t1[j] = (__bf16)ldf<ISBF>(Wx1, (kb + j) * Uu + col);
        t2[j] = (__bf16)ldf<ISBF>(Wh,  Uu * Uu + (kb + j) * Uu + col);
      }
      fWh0[e][s] = t0; fWx1f[e][s] = t1; fWh1[e][s] = t2;
    }
  }
  #pragma unroll
  for (int e = 0; e < 2; ++e) {
    #pragma unroll
    for (int s = 0; s < 8; ++s) {
      PIN8(fWh0[e][s]); PIN8(fWx1f[e][s]); PIN8(fWh1[e][s]);
    }
  }
  const float b1s = ldf<ISBF>(bias, Uu + wv * 32 + hf * 16 + m);  // this half's tile col

  // u fetch: lane reads tid32 = (wv>>1)*32 + (kc&1)*16 + m, slots (wv&1)*8..+7
  const int tid32u = (wv >> 1) * 32 + ((kc & 1) * 16) + m;
  const __bf16* Ubase = U + (size_t)tid32u * 16 + (wv & 1) * 8 + (size_t)rb * 2048;

  // full-wave write decomp: each half-wave writes tile e = hf, rows rgr+ii
  const int kc2 = m >> 3, j2 = m & 7, rgr = ((lane >> 4) & 1) * 4;
  const int toffw = wv * HCH + ((hf * 2 + kc2) * 8 + rgr) * 8 + j2;

  __syncthreads();   // drain U stores (vmcnt) + LDS staging

  bf16x8 u0 = *(const bf16x8*)(Ubase);   // u(0)

  // ---- prologue: h0_new(0) = tanh(u(0) + h0_init@Wh0) -> s_h0[1] ----
  {
    f32x4 d0 = {(float)u0[0], (float)u0[1], (float)u0[2], (float)u0[3]};
    f32x4 d1 = {(float)u0[4], (float)u0[5], (float)u0[6], (float)u0[7]};
    const __bf16* hb = s_h0 + au;
    #pragma unroll
    for (int s = 0; s < 8; ++s) {
      bf16x8 a = *(const bf16x8*)(hb + s * HCH);
      d0 = MFMA16(a, fWh0[0][s], d0);
      d1 = MFMA16(a, fWh0[1][s], d1);
    }
    u0 = *(const bf16x8*)(Ubase + (size_t)1 * 256 * 2048);  // prefetch u(1)
    __bf16* wp = s_h0 + HB + toffw;
    #pragma unroll
    for (int ii = 0; ii < 4; ++ii) {
      float dd = hf ? d1[ii] : d0[ii];   // upper half holds duplicate rows
      wp[ii * 8] = (__bf16)fast_tanh(dd);
    }
    barrier_lds();
  }

  for (int t = 0; t < Tt; ++t) {
    const int p = t & 1, pn = p ^ 1;
    int tf = (t + 2 < Tt) ? t + 2 : Tt - 1;
    bf16x8 un = *(const bf16x8*)(Ubase + (size_t)tf * 256 * 2048);

    const __bf16* h0b = s_h0 + pn * HB + au;   // h0_new(t)
    const __bf16* h1b = s_h1 + p * HB + au;    // h1(t)

    // depth-3 rotating A-frag prefetch: read for round s+3 issued at round s.
    bf16x8 A[3];
    A[0] = *(const bf16x8*)(h0b + 0 * HCH);
    A[1] = *(const bf16x8*)(h0b + 1 * HCH);
    A[2] = *(const bf16x8*)(h0b + 2 * HCH);

    // cBC = h0n@Wx1 + h1@Wh1 (K-concat, 16 chunks); cD = u + h0n@Wh0
    f32x4 cBC0 = {0.f,0.f,0.f,0.f}, cBC1 = {0.f,0.f,0.f,0.f};
    f32x4 cD0 = {(float)u0[0], (float)u0[1], (float)u0[2], (float)u0[3]};
    f32x4 cD1 = {(float)u0[4], (float)u0[5], (float)u0[6], (float)u0[7]};

    __bf16* wp0 = s_h0 + p * HB + toffw;       // h0_new(t+1)
    __bf16* wp1 = s_h1 + pn * HB + toffw;      // h1_new(t)

    __builtin_amdgcn_s_setprio(1);
    #pragma unroll
    for (int s = 0; s < 16; ++s) {
      bf16x8 a = A[s % 3];
      const int f = s + 3;
      if (f < 16)
        A[f % 3] = *(const bf16x8*)((f < 8) ? (h0b + f * HCH)
                                            : (h1b + (f - 8) * HCH));
      if (s < 8) {
        cBC0 = MFMA16(a, fWx1f[0][s], cBC0);
        cBC1 = MFMA16(a, fWx1f[1][s], cBC1);
        cD0  = MFMA16(a, fWh0[0][s], cD0);
        cD1  = MFMA16(a, fWh0[1][s], cD1);
      } else {
        cBC0 = MFMA16(a, fWh1[0][s - 8], cBC0);
        cBC1 = MFMA16(a, fWh1[1][s - 8], cBC1);
      }
      if (s == 7) {
        // early h0 write: cD complete; tanh+store overlap rounds 8-15.
        // Writes s_h0[p]; all concurrent reads are from s_h0[pn]/s_h1[p].
        #pragma unroll
        for (int ii = 0; ii < 4; ++ii) {
          float v0 = hf ? cD1[ii] : cD0[ii];   // upper half = duplicate rows
          wp0[ii * 8] = (__bf16)fast_tanh(v0);
        }
      }
    }
    __builtin_amdgcn_s_setprio(0);
    // tail: h1_new only (half-wave hf writes tile e=hf from duplicate accs)
    #pragma unroll
    for (int ii = 0; ii < 4; ++ii) {
      float v1 = hf ? cBC1[ii] : cBC0[ii];
      wp1[ii * 8] = (__bf16)fast_tanh(v1 + b1s);
    }
    u0 = un;
    barrier_lds();
  }

  // ---- epilogue: sigmoid(h1_new(79) @ Wo + bo); lives in s_h1[0] ----
  if (tid < 256) {
    const int r = tid >> 5, q = tid & 31;
    const __bf16* hp = s_h1 + (q >> 2) * HCH + ((q & 3) * 8 + r) * 8;
    bf16x8 hv = *(const bf16x8*)hp;
    float part = 0.f;
    #pragma unroll
    for (int j = 0; j < 8; ++j) part += (float)hv[j] * ldf<ISBF>(Wo, q * 8 + j);
    #pragma unroll
    for (int o = 16; o >= 1; o >>= 1) part += __shfl_down(part, o, 32);
    if (q == 0) {
      float z = part + ldf<ISBF>(bo, 0);
      float sg = 1.f / (1.f + __expf(-z));
      if constexpr (ISBF) ((__bf16*)out)[b0 + r] = (__bf16)sg;
      else                ((float*)out)[b0 + r]  = sg;
    }
  }
}

extern "C" void kernel_launch(void* const* d_in, const int* in_sizes, int n_in,
                              void* d_out, int out_size, void* d_ws, size_t ws_size,
                              hipStream_t stream) {
  const int*  tokens = (const int*)d_in[0];
  const void* emb = d_in[1];
  const void* Wx0 = d_in[2];
  const void* Wx1 = d_in[3];
  const void* Wh  = d_in[4];
  const void* b   = d_in[5];
  const void* h0  = d_in[6];
  const void* Wo  = d_in[7];
  const void* bo  = d_in[8];

  __bf16* U = (__bf16*)((char*)d_ws + 256);
  const size_t needU = 256 + (size_t)Tt * 256 * 2048 * sizeof(__bf16);  // ~84 MB
  if (ws_size < needU) return;

  rnn_kernel<true ><<<dim3(Bb / BM), dim3(RNT), 0, stream>>>(
      tokens, emb, Wx0, Wx1, Wh, b, h0, Wo, bo, U, d_out);
  rnn_kernel<false><<<dim3(Bb / BM), dim3(RNT), 0, stream>>>(
      tokens, emb, Wx0, Wx1, Wh, b, h0, Wo, bo, U, d_out);
}